// Round 6
// baseline (199.229 us; speedup 1.0000x reference)
//
#include <hip/hip_runtime.h>

typedef __bf16 bf16;
typedef unsigned int u32;
typedef __attribute__((ext_vector_type(8))) __bf16 bf16x8;
typedef __attribute__((ext_vector_type(4))) __bf16 bf16x4;
typedef __attribute__((ext_vector_type(4))) float floatx4;
typedef __attribute__((ext_vector_type(16))) float floatx16;
typedef __attribute__((ext_vector_type(4))) int int4v;

#define IN_DIM  768
#define ATT_DIM 512
#define NH      8
#define HD      64
#define BATCH   4
#define SEQ     2048
#define M_TOT   (BATCH*SEQ)     // 8192
#define QKV_N   (3*ATT_DIM)     // 1536

// Q scale: 1/sqrt(64) * log2(e)  -> scores exit MFMA in log2 domain
#define QSCALE 0.18033688011112042f

// async 16B global->LDS copy. LDS dest = wave-uniform base + lane*16.
__device__ __forceinline__ void cp16(void* lds, const void* g) {
    __builtin_amdgcn_global_load_lds((const __attribute__((address_space(1))) u32*)g,
                                     (__attribute__((address_space(3))) u32*)lds, 16, 0, 0);
}
// XOR-swizzled accessor for 64-col bf16 tiles staged by cp16:
// 16B chunk c (0..7) of row r lives at slot c ^ (r&7).
__device__ __forceinline__ const bf16* swz(const bf16* b, int row, int chunk) {
    return b + row * 64 + (((chunk) ^ (row & 7)) << 3);
}
// Conflict-free fragment read for attn tiles: global K/VT rows with bit3 set
// store their two 8B chunk-halves SWAPPED, so reading half "d-lo" at byte
// offset (row&8) and "d-hi" at (row&8)^8 spreads 32 rows over 16 (col,half)
// 2-bank groups -> 2-way (free) instead of 4-way b128. (R2: verified 0 conflicts)
__device__ __forceinline__ bf16x8 ld_swz8(const bf16* tile, int row, int chunk) {
    const char* base = (const char*)(tile + row * 64) + (((chunk ^ (row & 7)) << 4));
    const int off = row & 8;
    const bf16x4 h0 = *(const bf16x4*)(base + off);        // elems 0..3
    const bf16x4 h1 = *(const bf16x4*)(base + (off ^ 8));  // elems 4..7
    return (bf16x8){h0[0], h0[1], h0[2], h0[3], h1[0], h1[1], h1[2], h1[3]};
}

// pack two f32 -> one dword of 2 bf16 (low = lo, high = hi)
__device__ __forceinline__ int cvtpk_bf16(float lo, float hi) {
    int r;
    asm("v_cvt_pk_bf16_f32 %0, %1, %2" : "=v"(r) : "v"(lo), "v"(hi));
    return r;
}
// v_permlane32_swap_b32: a.hi-half <-> b.lo-half.
__device__ __forceinline__ void plswap(int& a, int& b) {
    asm("v_permlane32_swap_b32 %0, %1" : "+v"(a), "+v"(b));
}

// ---------------------------------------------------------------------------
// Kernel 0: fp32 -> bf16 conversion of X, W_qkv, W_out
// ---------------------------------------------------------------------------
#define N8_X  (M_TOT * IN_DIM / 8)
#define N8_WQ (QKV_N * IN_DIM / 8)
#define N8_WO (IN_DIM * ATT_DIM / 8)
#define N8_ALL (N8_X + N8_WQ + N8_WO)

__global__ __launch_bounds__(256) void cvt_all(const float* __restrict__ X,
                                               const float* __restrict__ Wq,
                                               const float* __restrict__ Wo,
                                               bf16* __restrict__ Xb,
                                               bf16* __restrict__ Wqb,
                                               bf16* __restrict__ Wob) {
    int i = blockIdx.x * 256 + threadIdx.x;
    const float* s; bf16* d; int off;
    if (i < N8_X)            { s = X;  d = Xb;  off = i; }
    else if (i < N8_X+N8_WQ) { s = Wq; d = Wqb; off = i - N8_X; }
    else                     { s = Wo; d = Wob; off = i - N8_X - N8_WQ; }
    const float4 a = ((const float4*)s)[2*off];
    const float4 b = ((const float4*)s)[2*off+1];
    bf16x8 o = {(bf16)a.x,(bf16)a.y,(bf16)a.z,(bf16)a.w,
                (bf16)b.x,(bf16)b.y,(bf16)b.z,(bf16)b.w};
    ((bf16x8*)d)[off] = o;
}

// ---------------------------------------------------------------------------
// Kernel 1: QKV = Xb * Wqkvb^T (bf16, DMA-staged, BK=64).
// Q -> [b][h][n][d] (pre-scaled); K -> same but 8B chunk-halves swapped for
// rows with n&8 (attn conflict-free reads); V -> [b][h][d][n] with 4-key
// halves swapped for d&8.  (Unchanged since R2 — verified passing.)
// ---------------------------------------------------------------------------
__global__ __launch_bounds__(256) void qkv_gemm(const bf16* __restrict__ Xb,
                                                const bf16* __restrict__ Wb,
                                                bf16* __restrict__ Q,
                                                bf16* __restrict__ Kv,
                                                bf16* __restrict__ VT) {
    __shared__ __align__(16) char smraw[34816];
    bf16* As = (bf16*)smraw;
    bf16* Bs = (bf16*)(smraw + 16384);

    const int tid  = threadIdx.x;
    const int bm0  = blockIdx.y * 128;
    const int bn0  = blockIdx.x * 128;
    const int wave = tid >> 6, lane = tid & 63;
    const int quad = lane >> 4, l15 = lane & 15;
    const int wm = (wave >> 1) * 64, wn = (wave & 1) * 64;
    const int r8 = lane >> 3, cc = (lane & 7) ^ r8;

    const bf16* ag = Xb + (size_t)(bm0 + wave * 32 + r8) * IN_DIM + cc * 8;
    const bf16* bg = Wb + (size_t)(bn0 + wave * 32 + r8) * IN_DIM + cc * 8;

    floatx4 acc[4][4];
#pragma unroll
    for (int i = 0; i < 4; ++i)
#pragma unroll
        for (int j = 0; j < 4; ++j) acc[i][j] = (floatx4){0.f, 0.f, 0.f, 0.f};

    for (int kt = 0; kt < IN_DIM / 64; ++kt) {
        __syncthreads();
#pragma unroll
        for (int it = 0; it < 4; ++it) {
            cp16(&As[(wave * 32 + it * 8) * 64], ag + it * (8 * IN_DIM) + kt * 64);
            cp16(&Bs[(wave * 32 + it * 8) * 64], bg + it * (8 * IN_DIM) + kt * 64);
        }
        __syncthreads();

        bf16x8 af[2][4], bfr[2][4];
#pragma unroll
        for (int kh = 0; kh < 2; ++kh)
#pragma unroll
            for (int i = 0; i < 4; ++i) {
                af[kh][i]  = *(const bf16x8*)swz(As, wm + i * 16 + l15, kh * 4 + quad);
                bfr[kh][i] = *(const bf16x8*)swz(Bs, wn + i * 16 + l15, kh * 4 + quad);
            }
#pragma unroll
        for (int kh = 0; kh < 2; ++kh)
#pragma unroll
            for (int i = 0; i < 4; ++i)
#pragma unroll
                for (int j = 0; j < 4; ++j)
                    acc[i][j] = __builtin_amdgcn_mfma_f32_16x16x32_bf16(af[kh][i], bfr[kh][j], acc[i][j], 0, 0, 0);
    }

    const int b = bm0 >> 11, nbase = bm0 & 2047;

    if (bn0 < 1024) {
#pragma unroll
        for (int i = 0; i < 4; ++i)
#pragma unroll
            for (int j = 0; j < 4; ++j)
#pragma unroll
                for (int r = 0; r < 4; ++r) {
                    const int row = bm0 + wm + i * 16 + quad * 4 + r;
                    const int col = bn0 + wn + j * 16 + l15;
                    const float v = acc[i][j][r];
                    const int rem = col & 511;
                    const int h = rem >> 6, d = rem & 63;
                    const int n = row & 2047;
                    const size_t idx = (((size_t)((row >> 11) * NH + h)) * SEQ + n) * HD + d;
                    if (col < 512) Q[idx] = (bf16)(v * QSCALE);
                    else           Kv[idx ^ (size_t)((n >> 1) & 4)] = (bf16)v;  // half-swap rows n&8
                }
    } else {
        __syncthreads();
        bf16 (*Ts)[136] = (bf16(*)[136])smraw;
#pragma unroll
        for (int i = 0; i < 4; ++i)
#pragma unroll
            for (int j = 0; j < 4; ++j) {
                bf16x4 pk = {(bf16)acc[i][j][0], (bf16)acc[i][j][1],
                             (bf16)acc[i][j][2], (bf16)acc[i][j][3]};
                *(bf16x4*)&Ts[wn + j * 16 + l15][wm + i * 16 + quad * 4] = pk;
            }
        __syncthreads();
        const int cb = bn0 - 1024;
#pragma unroll
        for (int t2 = 0; t2 < 8; ++t2) {
            const int id = tid + t2 * 256;
            const int c = id >> 4, nc = (id & 15) * 8;
            const int col = cb + c;
            const int h = col >> 6, d = col & 63;
            bf16x8 val = *(const bf16x8*)&Ts[c][nc];
            if (d & 8)  // half-swap rows d&8 (4-key halves within 8-key chunk)
                val = __builtin_shufflevector(val, val, 4, 5, 6, 7, 0, 1, 2, 3);
            *(bf16x8*)&VT[(((size_t)(b * NH + h)) * HD + d) * SEQ + nbase + nc] = val;
        }
    }
}

// ---------------------------------------------------------------------------
// Kernel 2: flash attention — SPLIT-K ACROSS BLOCKS (R6).
// Per-wave compute = R1's verified structure (4 waves x 32q, kb-loop inside)
// with R2's verified ld_swz8 conflict-free reads. grid (32 bh, 16 qt, 2 ks):
// each block processes keys [ks*1024, ks*1024+1024) and writes f32 partial
// (O, l) to workspace — NO intra-block cross-wave exchange (the R4/R5
// mechanism, condemned empirically). No-max softmax => partials over
// disjoint key sets are exactly additive; attn_combine merges.
// 1024 blocks -> 4 blocks/CU = 4 waves/SIMD (vs R1's 2). Total K/V DMA
// traffic unchanged (kt ranges disjoint). T5 setprio around MFMA clusters.
// ---------------------------------------------------------------------------
__global__ __launch_bounds__(256, 4) void attn(const bf16* __restrict__ Q,
                                               const bf16* __restrict__ K,
                                               const bf16* __restrict__ VT,
                                               float* __restrict__ Of,
                                               float* __restrict__ Lf) {
    __shared__ bf16 Ks[2][64 * 64];    // 16 KB: 64 keys x 64 d
    __shared__ bf16 VTs[2][64 * 64];   // 16 KB: 64 d x 64 keys

    const int tid  = threadIdx.x;
    const int wave = tid >> 6, lane = tid & 63;   // 4 waves x 32 q-rows
    const int l31  = lane & 31, hi = lane >> 5;
    const int bh = blockIdx.x;                 // bh fast dim: same-XCD L2 reuse
    const int q0 = blockIdx.y * 128;
    const int ks = blockIdx.z;                 // key-range half
    const int kt0 = ks * (SEQ / 128);          // 16 tiles of 64 keys each
    const bf16* Qg = Q  + (size_t)bh * SEQ * HD;
    const bf16* Kg = K  + (size_t)bh * SEQ * HD;
    const bf16* Vg = VT + (size_t)bh * HD * SEQ;

    // Q fragments for this wave's 32 q-rows
    bf16x8 aq[4];
    {
        const bf16* qrow = Qg + (size_t)(q0 + wave * 32 + l31) * HD;
#pragma unroll
        for (int c = 0; c < 4; ++c)
            aq[c] = *(const bf16x8*)(qrow + c * 16 + hi * 8);
    }

    // staging lanes: 8 rows x 8 chunks per cp16; 4 waves x 16 rows = 64 rows
    const int r8 = lane >> 3, cc8 = (lane & 7) ^ r8;
    const bf16* kgw = Kg + (size_t)(wave * 16 + r8) * HD + cc8 * 8;
    const bf16* vgw = Vg + (size_t)(wave * 16 + r8) * SEQ + cc8 * 8;

    float l = 0.f;
    floatx16 o[2];
#pragma unroll
    for (int i = 0; i < 16; ++i) { o[0][i] = 0.f; o[1][i] = 0.f; }

    // prologue: stage tile kt0 (64 keys: K 8KB + V 8KB, 4 cp16/thread)
#pragma unroll
    for (int it = 0; it < 2; ++it) {
        cp16(&Ks[0][(wave * 16 + it * 8) * 64],
             kgw + (size_t)(kt0 * 64 + it * 8) * HD);
        cp16(&VTs[0][(wave * 16 + it * 8) * 64],
             vgw + (size_t)(it * 8) * SEQ + kt0 * 64);
    }

    for (int kt = kt0; kt < kt0 + SEQ / 128; ++kt) {
        const int cur = kt & 1;   // kt0 is even -> buffer 0 first
        __syncthreads();   // drains DMA(kt) (issued one iter ago)
        if (kt < kt0 + SEQ / 128 - 1) {
#pragma unroll
            for (int it = 0; it < 2; ++it) {
                cp16(&Ks[cur ^ 1][(wave * 16 + it * 8) * 64],
                     kgw + (size_t)((kt + 1) * 64 + it * 8) * HD);
                cp16(&VTs[cur ^ 1][(wave * 16 + it * 8) * 64],
                     vgw + (size_t)(it * 8) * SEQ + (kt + 1) * 64);
            }
        }

#pragma unroll
        for (int kb = 0; kb < 2; ++kb) {
            const int krow = kb * 32 + l31;
            bf16x8 kf[4];
#pragma unroll
            for (int c = 0; c < 4; ++c)
                kf[c] = ld_swz8(Ks[cur], krow, c * 2 + hi);
            bf16x8 vf[2][2];
#pragma unroll
            for (int db = 0; db < 2; ++db) {
                vf[db][0] = ld_swz8(VTs[cur], db * 32 + l31, kb * 4 + hi);
                vf[db][1] = ld_swz8(VTs[cur], db * 32 + l31, kb * 4 + 2 + hi);
            }

            // S^T = K * Q : lane owns q-row l31, keys kb*32 + ...
            floatx16 s;
#pragma unroll
            for (int i = 0; i < 16; ++i) s[i] = 0.f;
            __builtin_amdgcn_s_setprio(1);
#pragma unroll
            for (int c = 0; c < 4; ++c)
                s = __builtin_amdgcn_mfma_f32_32x32x16_bf16(kf[c], aq[c], s, 0, 0, 0);
            __builtin_amdgcn_s_setprio(0);
            // softmax numerator in-register
            float p[16];
#pragma unroll
            for (int i = 0; i < 16; ++i) p[i] = __builtin_amdgcn_exp2f(s[i]);
            {
                const float t0 = (p[0] + p[1]) + (p[2] + p[3]);
                const float t1 = (p[4] + p[5]) + (p[6] + p[7]);
                const float t2 = (p[8] + p[9]) + (p[10] + p[11]);
                const float t3 = (p[12] + p[13]) + (p[14] + p[15]);
                l += (t0 + t1) + (t2 + t3);
            }
            int w[8];
#pragma unroll
            for (int i = 0; i < 8; ++i) w[i] = cvtpk_bf16(p[2 * i], p[2 * i + 1]);
            plswap(w[0], w[2]); plswap(w[1], w[3]);
            plswap(w[4], w[6]); plswap(w[5], w[7]);
            const int4v f0i = {w[0], w[1], w[2], w[3]};
            const int4v f1i = {w[4], w[5], w[6], w[7]};
            const bf16x8 f0 = __builtin_bit_cast(bf16x8, f0i);
            const bf16x8 f1 = __builtin_bit_cast(bf16x8, f1i);
            __builtin_amdgcn_s_setprio(1);
#pragma unroll
            for (int db = 0; db < 2; ++db) {
                o[db] = __builtin_amdgcn_mfma_f32_32x32x16_bf16(f0, vf[db][0], o[db], 0, 0, 0);
                o[db] = __builtin_amdgcn_mfma_f32_32x32x16_bf16(f1, vf[db][1], o[db], 0, 0, 0);
            }
            __builtin_amdgcn_s_setprio(0);
        }
    }

    // epilogue: write f32 partials (no inv, no cross-wave traffic)
    l += __shfl_xor(l, 32, 64);           // merge hi-halves: full key-half sum
    if (hi == 0)
        Lf[((size_t)ks * 32 + bh) * SEQ + q0 + wave * 32 + l31] = l;
#pragma unroll
    for (int reg = 0; reg < 16; ++reg) {
        const int qr = (reg & 3) + 8 * (reg >> 2) + 4 * hi;
        const int n = q0 + wave * 32 + qr;
        float* op = Of + (((size_t)ks * 32 + bh) * SEQ + n) * HD + l31;
        op[0]  = o[0][reg];
        op[32] = o[1][reg];
    }
}

// ---------------------------------------------------------------------------
// Kernel 2b: combine split-K partials: Y = (O0+O1)/(l0+l1), bf16.
// 32 bh x 2048 q x 8 d-octets = 524288 threads = 2048 blocks.
// ---------------------------------------------------------------------------
__global__ __launch_bounds__(256) void attn_combine(const float* __restrict__ Of,
                                                    const float* __restrict__ Lf,
                                                    bf16* __restrict__ Y) {
    const int i  = blockIdx.x * 256 + threadIdx.x;
    const int d0 = (i & 7) * 8;
    const int q  = (i >> 3) & 2047;
    const int bh = i >> 14;
    const float inv = 1.0f / (Lf[(size_t)bh * SEQ + q] +
                              Lf[(size_t)(32 + bh) * SEQ + q]);
    const float4 a0 = *(const float4*)&Of[(((size_t)bh * SEQ) + q) * HD + d0];
    const float4 a1 = *(const float4*)&Of[(((size_t)bh * SEQ) + q) * HD + d0 + 4];
    const float4 b0 = *(const float4*)&Of[(((size_t)(32 + bh) * SEQ) + q) * HD + d0];
    const float4 b1 = *(const float4*)&Of[(((size_t)(32 + bh) * SEQ) + q) * HD + d0 + 4];
    bf16x8 r = {(bf16)((a0.x + b0.x) * inv), (bf16)((a0.y + b0.y) * inv),
                (bf16)((a0.z + b0.z) * inv), (bf16)((a0.w + b0.w) * inv),
                (bf16)((a1.x + b1.x) * inv), (bf16)((a1.y + b1.y) * inv),
                (bf16)((a1.z + b1.z) * inv), (bf16)((a1.w + b1.w) * inv)};
    const int b = bh >> 3, h = bh & 7;
    *(bf16x8*)&Y[((size_t)(b * SEQ + q)) * ATT_DIM + h * HD + d0] = r;
}

// ---------------------------------------------------------------------------
// Kernel 3: out = Y * Woutb^T + b_out (bf16 DMA-staged, BK=64, fp32 out).
// ---------------------------------------------------------------------------
__global__ __launch_bounds__(256) void out_gemm(const bf16* __restrict__ Yb,
                                                const bf16* __restrict__ Wb,
                                                const float* __restrict__ bias,
                                                float* __restrict__ out) {
    __shared__ __align__(16) bf16 As[128 * 64];
    __shared__ __align__(16) bf16 Bs[128 * 64];

    const int tid  = threadIdx.x;
    const int bm0  = blockIdx.y * 128;
    const int bn0  = blockIdx.x * 128;
    const int wave = tid >> 6, lane = tid & 63;
    const int quad = lane >> 4, l15 = lane & 15;
    const int wm = (wave >> 1) * 64, wn = (wave & 1) * 64;
    const int r8 = lane >> 3, cc = (lane & 7) ^ r8;

    const bf16* ag = Yb + (size_t)(bm0 + wave * 32 + r8) * ATT_DIM + cc * 8;
    const bf16* bg = Wb + (size_t)(bn0 + wave * 32 + r8) * ATT_DIM + cc * 8;

    floatx4 acc[4][4];
#pragma unroll
    for (int i = 0; i < 4; ++i)
#pragma unroll
        for (int j = 0; j < 4; ++j) acc[i][j] = (floatx4){0.f, 0.f, 0.f, 0.f};

    for (int kt = 0; kt < ATT_DIM / 64; ++kt) {
        __syncthreads();
#pragma unroll
        for (int it = 0; it < 4; ++it) {
            cp16(&As[(wave * 32 + it * 8) * 64], ag + it * (8 * ATT_DIM) + kt * 64);
            cp16(&Bs[(wave * 32 + it * 8) * 64], bg + it * (8 * ATT_DIM) + kt * 64);
        }
        __syncthreads();

        bf16x8 af[2][4], bfr[2][4];
#pragma unroll
        for (int kh = 0; kh < 2; ++kh)
#pragma unroll
            for (int i = 0; i < 4; ++i) {
                af[kh][i]  = *(const bf16x8*)swz(As, wm + i * 16 + l15, kh * 4 + quad);
                bfr[kh][i] = *(const bf16x8*)swz(Bs, wn + i * 16 + l15, kh * 4 + quad);
            }
#pragma unroll
        for (int kh = 0; kh < 2; ++kh)
#pragma unroll
            for (int i = 0; i < 4; ++i)
#pragma unroll
                for (int j = 0; j < 4; ++j)
                    acc[i][j] = __builtin_amdgcn_mfma_f32_16x16x32_bf16(af[kh][i], bfr[kh][j], acc[i][j], 0, 0, 0);
    }

#pragma unroll
    for (int i = 0; i < 4; ++i)
#pragma unroll
        for (int j = 0; j < 4; ++j)
#pragma unroll
            for (int r = 0; r < 4; ++r) {
                const int row = bm0 + wm + i * 16 + quad * 4 + r;
                const int col = bn0 + wn + j * 16 + l15;
                out[(size_t)row * IN_DIM + col] = acc[i][j][r] + bias[col];
            }
}

// ---------------------------------------------------------------------------
extern "C" void kernel_launch(void* const* d_in, const int* in_sizes, int n_in,
                              void* d_out, int out_size, void* d_ws, size_t ws_size,
                              hipStream_t stream) {
    const float* X    = (const float*)d_in[0];
    const float* Wqkv = (const float*)d_in[1];
    const float* Wout = (const float*)d_in[2];
    const float* bout = (const float*)d_in[3];
    float* out = (float*)d_out;

    char* ws = (char*)d_ws;
    size_t off = 0;
    bf16* Xb  = (bf16*)(ws + off); off += (size_t)M_TOT * IN_DIM * 2;
    bf16* Wqb = (bf16*)(ws + off); off += (size_t)QKV_N * IN_DIM * 2;
    bf16* Wob = (bf16*)(ws + off); off += (size_t)IN_DIM * ATT_DIM * 2;
    const size_t T = (size_t)BATCH * NH * SEQ * HD * 2;
    bf16* Q  = (bf16*)(ws + off); off += T;
    bf16* K  = (bf16*)(ws + off); off += T;
    bf16* VT = (bf16*)(ws + off); off += T;
    bf16* Y  = (bf16*)(ws + off); off += T;
    // split-K partials: O f32 [2][32][2048][64], l f32 [2][32][2048]
    float* Of = (float*)(ws + off); off += (size_t)2 * 32 * SEQ * HD * 4;
    float* Lf = (float*)(ws + off); off += (size_t)2 * 32 * SEQ * 4;

    cvt_all<<<N8_ALL / 256, 256, 0, stream>>>(X, Wqkv, Wout, Xb, Wqb, Wob);
    qkv_gemm<<<dim3(QKV_N / 128, M_TOT / 128), 256, 0, stream>>>(Xb, Wqb, Q, K, VT);
    attn<<<dim3(BATCH * NH, SEQ / 128, 2), 256, 0, stream>>>(Q, K, VT, Of, Lf);
    attn_combine<<<(32 * SEQ * 8) / 256, 256, 0, stream>>>(Of, Lf, Y);
    out_gemm<<<dim3(IN_DIM / 128, M_TOT / 128), 256, 0, stream>>>(Y, Wob, bout, out);
}

// Round 7
// 174.988 us; speedup vs baseline: 1.1385x; 1.1385x over previous
//
#include <hip/hip_runtime.h>

typedef __bf16 bf16;
typedef unsigned int u32;
typedef __attribute__((ext_vector_type(8))) __bf16 bf16x8;
typedef __attribute__((ext_vector_type(4))) __bf16 bf16x4;
typedef __attribute__((ext_vector_type(4))) float floatx4;
typedef __attribute__((ext_vector_type(16))) float floatx16;
typedef __attribute__((ext_vector_type(4))) int int4v;

#define IN_DIM  768
#define ATT_DIM 512
#define NH      8
#define HD      64
#define BATCH   4
#define SEQ     2048
#define M_TOT   (BATCH*SEQ)     // 8192
#define QKV_N   (3*ATT_DIM)     // 1536

// Q scale: 1/sqrt(64) * log2(e)  -> scores exit MFMA in log2 domain
#define QSCALE 0.18033688011112042f

// async 16B global->LDS copy. LDS dest = wave-uniform base + lane*16.
__device__ __forceinline__ void cp16(void* lds, const void* g) {
    __builtin_amdgcn_global_load_lds((const __attribute__((address_space(1))) u32*)g,
                                     (__attribute__((address_space(3))) u32*)lds, 16, 0, 0);
}
// XOR-swizzled accessor for 64-col bf16 tiles staged by cp16:
// 16B chunk c (0..7) of row r lives at slot c ^ (r&7).
__device__ __forceinline__ const bf16* swz(const bf16* b, int row, int chunk) {
    return b + row * 64 + (((chunk) ^ (row & 7)) << 3);
}
// Conflict-free fragment read for attn tiles: global K/VT rows with bit3 set
// store their two 8B chunk-halves SWAPPED, so reading half "d-lo" at byte
// offset (row&8) and "d-hi" at (row&8)^8 spreads 32 rows over 16 (col,half)
// 2-bank groups -> 2-way (free) instead of 4-way b128. (R2: verified 0 conflicts)
__device__ __forceinline__ bf16x8 ld_swz8(const bf16* tile, int row, int chunk) {
    const char* base = (const char*)(tile + row * 64) + (((chunk ^ (row & 7)) << 4));
    const int off = row & 8;
    const bf16x4 h0 = *(const bf16x4*)(base + off);        // elems 0..3
    const bf16x4 h1 = *(const bf16x4*)(base + (off ^ 8));  // elems 4..7
    return (bf16x8){h0[0], h0[1], h0[2], h0[3], h1[0], h1[1], h1[2], h1[3]};
}

// pack two f32 -> one dword of 2 bf16 (low = lo, high = hi)
__device__ __forceinline__ int cvtpk_bf16(float lo, float hi) {
    int r;
    asm("v_cvt_pk_bf16_f32 %0, %1, %2" : "=v"(r) : "v"(lo), "v"(hi));
    return r;
}
// v_permlane32_swap_b32: a.hi-half <-> b.lo-half.
__device__ __forceinline__ void plswap(int& a, int& b) {
    asm("v_permlane32_swap_b32 %0, %1" : "+v"(a), "+v"(b));
}

// ---------------------------------------------------------------------------
// Kernel 0: fp32 -> bf16 conversion of X, W_qkv, W_out
// ---------------------------------------------------------------------------
#define N8_X  (M_TOT * IN_DIM / 8)
#define N8_WQ (QKV_N * IN_DIM / 8)
#define N8_WO (IN_DIM * ATT_DIM / 8)
#define N8_ALL (N8_X + N8_WQ + N8_WO)

__global__ __launch_bounds__(256) void cvt_all(const float* __restrict__ X,
                                               const float* __restrict__ Wq,
                                               const float* __restrict__ Wo,
                                               bf16* __restrict__ Xb,
                                               bf16* __restrict__ Wqb,
                                               bf16* __restrict__ Wob) {
    int i = blockIdx.x * 256 + threadIdx.x;
    const float* s; bf16* d; int off;
    if (i < N8_X)            { s = X;  d = Xb;  off = i; }
    else if (i < N8_X+N8_WQ) { s = Wq; d = Wqb; off = i - N8_X; }
    else                     { s = Wo; d = Wob; off = i - N8_X - N8_WQ; }
    const float4 a = ((const float4*)s)[2*off];
    const float4 b = ((const float4*)s)[2*off+1];
    bf16x8 o = {(bf16)a.x,(bf16)a.y,(bf16)a.z,(bf16)a.w,
                (bf16)b.x,(bf16)b.y,(bf16)b.z,(bf16)b.w};
    ((bf16x8*)d)[off] = o;
}

// ---------------------------------------------------------------------------
// Kernel 1: QKV = Xb * Wqkvb^T (bf16, DMA-staged, BK=64).
// Q -> [b][h][n][d] (pre-scaled); K -> same but 8B chunk-halves swapped for
// rows with n&8 (attn conflict-free reads); V -> [b][h][d][n] with 4-key
// halves swapped for d&8.  R7: block-uniform Q/K branch (cols of a 128-wide
// block never straddle 512), replacing the per-element predicate.
// ---------------------------------------------------------------------------
__global__ __launch_bounds__(256) void qkv_gemm(const bf16* __restrict__ Xb,
                                                const bf16* __restrict__ Wb,
                                                bf16* __restrict__ Q,
                                                bf16* __restrict__ Kv,
                                                bf16* __restrict__ VT) {
    __shared__ __align__(16) char smraw[34816];
    bf16* As = (bf16*)smraw;
    bf16* Bs = (bf16*)(smraw + 16384);

    const int tid  = threadIdx.x;
    const int bm0  = blockIdx.y * 128;
    const int bn0  = blockIdx.x * 128;
    const int wave = tid >> 6, lane = tid & 63;
    const int quad = lane >> 4, l15 = lane & 15;
    const int wm = (wave >> 1) * 64, wn = (wave & 1) * 64;
    const int r8 = lane >> 3, cc = (lane & 7) ^ r8;

    const bf16* ag = Xb + (size_t)(bm0 + wave * 32 + r8) * IN_DIM + cc * 8;
    const bf16* bg = Wb + (size_t)(bn0 + wave * 32 + r8) * IN_DIM + cc * 8;

    floatx4 acc[4][4];
#pragma unroll
    for (int i = 0; i < 4; ++i)
#pragma unroll
        for (int j = 0; j < 4; ++j) acc[i][j] = (floatx4){0.f, 0.f, 0.f, 0.f};

    for (int kt = 0; kt < IN_DIM / 64; ++kt) {
        __syncthreads();
#pragma unroll
        for (int it = 0; it < 4; ++it) {
            cp16(&As[(wave * 32 + it * 8) * 64], ag + it * (8 * IN_DIM) + kt * 64);
            cp16(&Bs[(wave * 32 + it * 8) * 64], bg + it * (8 * IN_DIM) + kt * 64);
        }
        __syncthreads();

        bf16x8 af[2][4], bfr[2][4];
#pragma unroll
        for (int kh = 0; kh < 2; ++kh)
#pragma unroll
            for (int i = 0; i < 4; ++i) {
                af[kh][i]  = *(const bf16x8*)swz(As, wm + i * 16 + l15, kh * 4 + quad);
                bfr[kh][i] = *(const bf16x8*)swz(Bs, wn + i * 16 + l15, kh * 4 + quad);
            }
#pragma unroll
        for (int kh = 0; kh < 2; ++kh)
#pragma unroll
            for (int i = 0; i < 4; ++i)
#pragma unroll
                for (int j = 0; j < 4; ++j)
                    acc[i][j] = __builtin_amdgcn_mfma_f32_16x16x32_bf16(af[kh][i], bfr[kh][j], acc[i][j], 0, 0, 0);
    }

    const int b = bm0 >> 11, nbase = bm0 & 2047;

    if (bn0 < 512) {            // pure-Q block
#pragma unroll
        for (int i = 0; i < 4; ++i)
#pragma unroll
            for (int j = 0; j < 4; ++j)
#pragma unroll
                for (int r = 0; r < 4; ++r) {
                    const int row = bm0 + wm + i * 16 + quad * 4 + r;
                    const int col = bn0 + wn + j * 16 + l15;
                    const int h = col >> 6, d = col & 63;
                    const int n = row & 2047;
                    const size_t idx = (((size_t)((row >> 11) * NH + h)) * SEQ + n) * HD + d;
                    Q[idx] = (bf16)(acc[i][j][r] * QSCALE);
                }
    } else if (bn0 < 1024) {    // pure-K block (half-swap rows n&8)
#pragma unroll
        for (int i = 0; i < 4; ++i)
#pragma unroll
            for (int j = 0; j < 4; ++j)
#pragma unroll
                for (int r = 0; r < 4; ++r) {
                    const int row = bm0 + wm + i * 16 + quad * 4 + r;
                    const int col = bn0 - 512 + wn + j * 16 + l15;
                    const int h = col >> 6, d = col & 63;
                    const int n = row & 2047;
                    const size_t idx = (((size_t)((row >> 11) * NH + h)) * SEQ + n) * HD + d;
                    Kv[idx ^ (size_t)((n >> 1) & 4)] = (bf16)acc[i][j][r];
                }
    } else {
        __syncthreads();
        bf16 (*Ts)[136] = (bf16(*)[136])smraw;
#pragma unroll
        for (int i = 0; i < 4; ++i)
#pragma unroll
            for (int j = 0; j < 4; ++j) {
                bf16x4 pk = {(bf16)acc[i][j][0], (bf16)acc[i][j][1],
                             (bf16)acc[i][j][2], (bf16)acc[i][j][3]};
                *(bf16x4*)&Ts[wn + j * 16 + l15][wm + i * 16 + quad * 4] = pk;
            }
        __syncthreads();
        const int cb = bn0 - 1024;
#pragma unroll
        for (int t2 = 0; t2 < 8; ++t2) {
            const int id = tid + t2 * 256;
            const int c = id >> 4, nc = (id & 15) * 8;
            const int col = cb + c;
            const int h = col >> 6, d = col & 63;
            bf16x8 val = *(const bf16x8*)&Ts[c][nc];
            if (d & 8)  // half-swap rows d&8 (4-key halves within 8-key chunk)
                val = __builtin_shufflevector(val, val, 4, 5, 6, 7, 0, 1, 2, 3);
            *(bf16x8*)&VT[(((size_t)(b * NH + h)) * HD + d) * SEQ + nbase + nc] = val;
        }
    }
}

// ---------------------------------------------------------------------------
// Kernel 2: flash attention (R7). Verified R1/R6 shape: 512 blocks
// (32 bh x 16 qt), 4 waves x 32 q-rows, full key range per block, kb-loop
// inside, ld_swz8 conflict-free reads, direct-Y epilogue (R1-verified).
// NEW: ILP fixes for the 44% issue-idle — split QK accumulator (s0/s1,
// halves the dependent MFMA chain) and split PV accumulator (oa/ob,
// makes the two PV MFMAs per db independent; merged in epilogue).
// T5 setprio around MFMA clusters.
// ---------------------------------------------------------------------------
__global__ __launch_bounds__(256, 2) void attn(const bf16* __restrict__ Q,
                                               const bf16* __restrict__ K,
                                               const bf16* __restrict__ VT,
                                               bf16* __restrict__ Y) {
    __shared__ bf16 Ks[2][64 * 64];    // 16 KB: 64 keys x 64 d
    __shared__ bf16 VTs[2][64 * 64];   // 16 KB: 64 d x 64 keys

    const int tid  = threadIdx.x;
    const int wave = tid >> 6, lane = tid & 63;   // 4 waves x 32 q-rows
    const int l31  = lane & 31, hi = lane >> 5;
    const int bh = blockIdx.x;                 // bh fast dim: same-XCD L2 reuse
    const int q0 = blockIdx.y * 128;
    const bf16* Qg = Q  + (size_t)bh * SEQ * HD;
    const bf16* Kg = K  + (size_t)bh * SEQ * HD;
    const bf16* Vg = VT + (size_t)bh * HD * SEQ;

    // Q fragments for this wave's 32 q-rows
    bf16x8 aq[4];
    {
        const bf16* qrow = Qg + (size_t)(q0 + wave * 32 + l31) * HD;
#pragma unroll
        for (int c = 0; c < 4; ++c)
            aq[c] = *(const bf16x8*)(qrow + c * 16 + hi * 8);
    }

    // staging lanes: 8 rows x 8 chunks per cp16; 4 waves x 16 rows = 64 rows
    const int r8 = lane >> 3, cc8 = (lane & 7) ^ r8;
    const bf16* kgw = Kg + (size_t)(wave * 16 + r8) * HD + cc8 * 8;
    const bf16* vgw = Vg + (size_t)(wave * 16 + r8) * SEQ + cc8 * 8;

    float l = 0.f;
    floatx16 oa[2], ob[2];
#pragma unroll
    for (int i = 0; i < 16; ++i) {
        oa[0][i] = 0.f; oa[1][i] = 0.f;
        ob[0][i] = 0.f; ob[1][i] = 0.f;
    }

    // prologue: stage tile 0 (64 keys: K 8KB + V 8KB, 4 cp16/thread)
#pragma unroll
    for (int it = 0; it < 2; ++it) {
        cp16(&Ks[0][(wave * 16 + it * 8) * 64], kgw + (size_t)(it * 8) * HD);
        cp16(&VTs[0][(wave * 16 + it * 8) * 64], vgw + (size_t)(it * 8) * SEQ);
    }

    for (int kt = 0; kt < SEQ / 64; ++kt) {
        const int cur = kt & 1;
        __syncthreads();   // drains DMA(kt) (issued one iter ago)
        if (kt < SEQ / 64 - 1) {
#pragma unroll
            for (int it = 0; it < 2; ++it) {
                cp16(&Ks[cur ^ 1][(wave * 16 + it * 8) * 64],
                     kgw + (size_t)((kt + 1) * 64 + it * 8) * HD);
                cp16(&VTs[cur ^ 1][(wave * 16 + it * 8) * 64],
                     vgw + (size_t)(it * 8) * SEQ + (kt + 1) * 64);
            }
        }

#pragma unroll
        for (int kb = 0; kb < 2; ++kb) {
            const int krow = kb * 32 + l31;
            bf16x8 kf[4];
#pragma unroll
            for (int c = 0; c < 4; ++c)
                kf[c] = ld_swz8(Ks[cur], krow, c * 2 + hi);
            bf16x8 vf[2][2];
#pragma unroll
            for (int db = 0; db < 2; ++db) {
                vf[db][0] = ld_swz8(VTs[cur], db * 32 + l31, kb * 4 + hi);
                vf[db][1] = ld_swz8(VTs[cur], db * 32 + l31, kb * 4 + 2 + hi);
            }

            // S^T = K * Q : split accumulator halves the dependent chain
            floatx16 s0, s1;
#pragma unroll
            for (int i = 0; i < 16; ++i) { s0[i] = 0.f; s1[i] = 0.f; }
            __builtin_amdgcn_s_setprio(1);
            s0 = __builtin_amdgcn_mfma_f32_32x32x16_bf16(kf[0], aq[0], s0, 0, 0, 0);
            s1 = __builtin_amdgcn_mfma_f32_32x32x16_bf16(kf[1], aq[1], s1, 0, 0, 0);
            s0 = __builtin_amdgcn_mfma_f32_32x32x16_bf16(kf[2], aq[2], s0, 0, 0, 0);
            s1 = __builtin_amdgcn_mfma_f32_32x32x16_bf16(kf[3], aq[3], s1, 0, 0, 0);
            __builtin_amdgcn_s_setprio(0);
            // softmax numerator in-register
            float p[16];
#pragma unroll
            for (int i = 0; i < 16; ++i)
                p[i] = __builtin_amdgcn_exp2f(s0[i] + s1[i]);
            {
                const float t0 = (p[0] + p[1]) + (p[2] + p[3]);
                const float t1 = (p[4] + p[5]) + (p[6] + p[7]);
                const float t2 = (p[8] + p[9]) + (p[10] + p[11]);
                const float t3 = (p[12] + p[13]) + (p[14] + p[15]);
                l += (t0 + t1) + (t2 + t3);
            }
            int w[8];
#pragma unroll
            for (int i = 0; i < 8; ++i) w[i] = cvtpk_bf16(p[2 * i], p[2 * i + 1]);
            plswap(w[0], w[2]); plswap(w[1], w[3]);
            plswap(w[4], w[6]); plswap(w[5], w[7]);
            const int4v f0i = {w[0], w[1], w[2], w[3]};
            const int4v f1i = {w[4], w[5], w[6], w[7]};
            const bf16x8 f0 = __builtin_bit_cast(bf16x8, f0i);
            const bf16x8 f1 = __builtin_bit_cast(bf16x8, f1i);
            // O += P * V : independent oa/ob chains (merged in epilogue)
            __builtin_amdgcn_s_setprio(1);
#pragma unroll
            for (int db = 0; db < 2; ++db) {
                oa[db] = __builtin_amdgcn_mfma_f32_32x32x16_bf16(f0, vf[db][0], oa[db], 0, 0, 0);
                ob[db] = __builtin_amdgcn_mfma_f32_32x32x16_bf16(f1, vf[db][1], ob[db], 0, 0, 0);
            }
            __builtin_amdgcn_s_setprio(0);
        }
    }

    // epilogue (R1-verified): finish row sums, distribute 1/l, write Y
    l += __shfl_xor(l, 32, 64);           // merge hi-halves: full 2048-key sum
    const float inv = 1.0f / l;
    const int b = bh >> 3, h = bh & 7;
#pragma unroll
    for (int reg = 0; reg < 16; ++reg) {
        const int qr = (reg & 3) + 8 * (reg >> 2) + 4 * hi;
        const float li = __int_as_float(
            __builtin_amdgcn_ds_bpermute(qr << 2, __float_as_int(inv)));
        const int n = q0 + wave * 32 + qr;
        bf16* yrow = Y + ((size_t)(b * SEQ + n)) * ATT_DIM + h * HD + l31;
        yrow[0]  = (bf16)((oa[0][reg] + ob[0][reg]) * li);
        yrow[32] = (bf16)((oa[1][reg] + ob[1][reg]) * li);
    }
}

// ---------------------------------------------------------------------------
// Kernel 3: out = Y * Woutb^T + b_out (bf16 DMA-staged, BK=64, fp32 out).
// ---------------------------------------------------------------------------
__global__ __launch_bounds__(256) void out_gemm(const bf16* __restrict__ Yb,
                                                const bf16* __restrict__ Wb,
                                                const float* __restrict__ bias,
                                                float* __restrict__ out) {
    __shared__ __align__(16) bf16 As[128 * 64];
    __shared__ __align__(16) bf16 Bs[128 * 64];

    const int tid  = threadIdx.x;
    const int bm0  = blockIdx.y * 128;
    const int bn0  = blockIdx.x * 128;
    const int wave = tid >> 6, lane = tid & 63;
    const int quad = lane >> 4, l15 = lane & 15;
    const int wm = (wave >> 1) * 64, wn = (wave & 1) * 64;
    const int r8 = lane >> 3, cc = (lane & 7) ^ r8;

    const bf16* ag = Yb + (size_t)(bm0 + wave * 32 + r8) * ATT_DIM + cc * 8;
    const bf16* bg = Wb + (size_t)(bn0 + wave * 32 + r8) * ATT_DIM + cc * 8;

    floatx4 acc[4][4];
#pragma unroll
    for (int i = 0; i < 4; ++i)
#pragma unroll
        for (int j = 0; j < 4; ++j) acc[i][j] = (floatx4){0.f, 0.f, 0.f, 0.f};

    for (int kt = 0; kt < ATT_DIM / 64; ++kt) {
        __syncthreads();
#pragma unroll
        for (int it = 0; it < 4; ++it) {
            cp16(&As[(wave * 32 + it * 8) * 64], ag + it * (8 * ATT_DIM) + kt * 64);
            cp16(&Bs[(wave * 32 + it * 8) * 64], bg + it * (8 * ATT_DIM) + kt * 64);
        }
        __syncthreads();

        bf16x8 af[2][4], bfr[2][4];
#pragma unroll
        for (int kh = 0; kh < 2; ++kh)
#pragma unroll
            for (int i = 0; i < 4; ++i) {
                af[kh][i]  = *(const bf16x8*)swz(As, wm + i * 16 + l15, kh * 4 + quad);
                bfr[kh][i] = *(const bf16x8*)swz(Bs, wn + i * 16 + l15, kh * 4 + quad);
            }
#pragma unroll
        for (int kh = 0; kh < 2; ++kh)
#pragma unroll
            for (int i = 0; i < 4; ++i)
#pragma unroll
                for (int j = 0; j < 4; ++j)
                    acc[i][j] = __builtin_amdgcn_mfma_f32_16x16x32_bf16(af[kh][i], bfr[kh][j], acc[i][j], 0, 0, 0);
    }

#pragma unroll
    for (int i = 0; i < 4; ++i)
#pragma unroll
        for (int j = 0; j < 4; ++j)
#pragma unroll
            for (int r = 0; r < 4; ++r) {
                const int row = bm0 + wm + i * 16 + quad * 4 + r;
                const int col = bn0 + wn + j * 16 + l15;
                out[(size_t)row * IN_DIM + col] = acc[i][j][r] + bias[col];
            }
}

// ---------------------------------------------------------------------------
extern "C" void kernel_launch(void* const* d_in, const int* in_sizes, int n_in,
                              void* d_out, int out_size, void* d_ws, size_t ws_size,
                              hipStream_t stream) {
    const float* X    = (const float*)d_in[0];
    const float* Wqkv = (const float*)d_in[1];
    const float* Wout = (const float*)d_in[2];
    const float* bout = (const float*)d_in[3];
    float* out = (float*)d_out;

    char* ws = (char*)d_ws;
    size_t off = 0;
    bf16* Xb  = (bf16*)(ws + off); off += (size_t)M_TOT * IN_DIM * 2;
    bf16* Wqb = (bf16*)(ws + off); off += (size_t)QKV_N * IN_DIM * 2;
    bf16* Wob = (bf16*)(ws + off); off += (size_t)IN_DIM * ATT_DIM * 2;
    const size_t T = (size_t)BATCH * NH * SEQ * HD * 2;
    bf16* Q  = (bf16*)(ws + off); off += T;
    bf16* K  = (bf16*)(ws + off); off += T;
    bf16* VT = (bf16*)(ws + off); off += T;
    bf16* Y  = (bf16*)(ws + off); off += T;

    cvt_all<<<N8_ALL / 256, 256, 0, stream>>>(X, Wqkv, Wout, Xb, Wqb, Wob);
    qkv_gemm<<<dim3(QKV_N / 128, M_TOT / 128), 256, 0, stream>>>(Xb, Wqb, Q, K, VT);
    attn<<<dim3(BATCH * NH, SEQ / 128), 256, 0, stream>>>(Q, K, VT, Y);
    out_gemm<<<dim3(IN_DIM / 128, M_TOT / 128), 256, 0, stream>>>(Y, Wob, bout, out);
}

// Round 8
// 166.992 us; speedup vs baseline: 1.1930x; 1.0479x over previous
//
#include <hip/hip_runtime.h>

typedef __bf16 bf16;
typedef unsigned int u32;
typedef __attribute__((ext_vector_type(8))) __bf16 bf16x8;
typedef __attribute__((ext_vector_type(4))) __bf16 bf16x4;
typedef __attribute__((ext_vector_type(4))) float floatx4;
typedef __attribute__((ext_vector_type(16))) float floatx16;
typedef __attribute__((ext_vector_type(4))) int int4v;

#define IN_DIM  768
#define ATT_DIM 512
#define NH      8
#define HD      64
#define BATCH   4
#define SEQ     2048
#define M_TOT   (BATCH*SEQ)     // 8192
#define QKV_N   (3*ATT_DIM)     // 1536

// Q scale: 1/sqrt(64) * log2(e)  -> scores exit MFMA in log2 domain
#define QSCALE 0.18033688011112042f

// async 16B global->LDS copy. LDS dest = wave-uniform base + lane*16.
__device__ __forceinline__ void cp16(void* lds, const void* g) {
    __builtin_amdgcn_global_load_lds((const __attribute__((address_space(1))) u32*)g,
                                     (__attribute__((address_space(3))) u32*)lds, 16, 0, 0);
}
// XOR-swizzled accessor for 64-col bf16 tiles staged by cp16:
// 16B chunk c (0..7) of row r lives at slot c ^ (r&7).
__device__ __forceinline__ const bf16* swz(const bf16* b, int row, int chunk) {
    return b + row * 64 + (((chunk) ^ (row & 7)) << 3);
}
// Conflict-free fragment read for attn tiles: global K/VT rows with bit3 set
// store their two 8B chunk-halves SWAPPED, so reading half "d-lo" at byte
// offset (row&8) and "d-hi" at (row&8)^8 spreads 32 rows over 16 (col,half)
// 2-bank groups. (R2: 0 conflicts @2 waves; R6/R7: halves conflicts @4 waves)
__device__ __forceinline__ bf16x8 ld_swz8(const bf16* tile, int row, int chunk) {
    const char* base = (const char*)(tile + row * 64) + (((chunk ^ (row & 7)) << 4));
    const int off = row & 8;
    const bf16x4 h0 = *(const bf16x4*)(base + off);        // elems 0..3
    const bf16x4 h1 = *(const bf16x4*)(base + (off ^ 8));  // elems 4..7
    return (bf16x8){h0[0], h0[1], h0[2], h0[3], h1[0], h1[1], h1[2], h1[3]};
}

// pack two f32 -> one dword of 2 bf16 (low = lo, high = hi)
__device__ __forceinline__ int cvtpk_bf16(float lo, float hi) {
    int r;
    asm("v_cvt_pk_bf16_f32 %0, %1, %2" : "=v"(r) : "v"(lo), "v"(hi));
    return r;
}
// v_permlane32_swap_b32: a.hi-half <-> b.lo-half.
__device__ __forceinline__ void plswap(int& a, int& b) {
    asm("v_permlane32_swap_b32 %0, %1" : "+v"(a), "+v"(b));
}

// ---------------------------------------------------------------------------
// Kernel 0: fp32 -> bf16 conversion of X, W_qkv, W_out
// ---------------------------------------------------------------------------
#define N8_X  (M_TOT * IN_DIM / 8)
#define N8_WQ (QKV_N * IN_DIM / 8)
#define N8_WO (IN_DIM * ATT_DIM / 8)
#define N8_ALL (N8_X + N8_WQ + N8_WO)

__global__ __launch_bounds__(256) void cvt_all(const float* __restrict__ X,
                                               const float* __restrict__ Wq,
                                               const float* __restrict__ Wo,
                                               bf16* __restrict__ Xb,
                                               bf16* __restrict__ Wqb,
                                               bf16* __restrict__ Wob) {
    int i = blockIdx.x * 256 + threadIdx.x;
    const float* s; bf16* d; int off;
    if (i < N8_X)            { s = X;  d = Xb;  off = i; }
    else if (i < N8_X+N8_WQ) { s = Wq; d = Wqb; off = i - N8_X; }
    else                     { s = Wo; d = Wob; off = i - N8_X - N8_WQ; }
    const float4 a = ((const float4*)s)[2*off];
    const float4 b = ((const float4*)s)[2*off+1];
    bf16x8 o = {(bf16)a.x,(bf16)a.y,(bf16)a.z,(bf16)a.w,
                (bf16)b.x,(bf16)b.y,(bf16)b.z,(bf16)b.w};
    ((bf16x8*)d)[off] = o;
}

// ---------------------------------------------------------------------------
// Kernel 1: QKV = Xb * Wqkvb^T (bf16, DMA-staged, BK=64).
// R8: T1 XCD-chunked block swizzle — each XCD gets 8 contiguous M-panels x
// all 12 N-blocks, so B (2.25 MB) is L2-resident per XCD and each A panel
// is fetched by exactly one XCD. nwg=768, 768%8==0 -> bijective.
// Q -> [b][h][n][d] (pre-scaled); K -> n&8 half-swap; V -> [b][h][d][n],
// d&8 half-swap (attn conflict-free reads). Epilogue branches block-uniform.
// ---------------------------------------------------------------------------
__global__ __launch_bounds__(256) void qkv_gemm(const bf16* __restrict__ Xb,
                                                const bf16* __restrict__ Wb,
                                                bf16* __restrict__ Q,
                                                bf16* __restrict__ Kv,
                                                bf16* __restrict__ VT) {
    __shared__ __align__(16) char smraw[34816];
    bf16* As = (bf16*)smraw;
    bf16* Bs = (bf16*)(smraw + 16384);

    const int tid  = threadIdx.x;
    // XCD-chunked swizzle: dispatch id -> tile id (96 tiles per XCD chunk)
    const int id  = blockIdx.y * 12 + blockIdx.x;   // gridDim.x == 12
    const int nid = (id & 7) * 96 + (id >> 3);
    const int bm0 = (nid / 12) * 128;
    const int bn0 = (nid % 12) * 128;
    const int wave = tid >> 6, lane = tid & 63;
    const int quad = lane >> 4, l15 = lane & 15;
    const int wm = (wave >> 1) * 64, wn = (wave & 1) * 64;
    const int r8 = lane >> 3, cc = (lane & 7) ^ r8;

    const bf16* ag = Xb + (size_t)(bm0 + wave * 32 + r8) * IN_DIM + cc * 8;
    const bf16* bg = Wb + (size_t)(bn0 + wave * 32 + r8) * IN_DIM + cc * 8;

    floatx4 acc[4][4];
#pragma unroll
    for (int i = 0; i < 4; ++i)
#pragma unroll
        for (int j = 0; j < 4; ++j) acc[i][j] = (floatx4){0.f, 0.f, 0.f, 0.f};

    for (int kt = 0; kt < IN_DIM / 64; ++kt) {
        __syncthreads();
#pragma unroll
        for (int it = 0; it < 4; ++it) {
            cp16(&As[(wave * 32 + it * 8) * 64], ag + it * (8 * IN_DIM) + kt * 64);
            cp16(&Bs[(wave * 32 + it * 8) * 64], bg + it * (8 * IN_DIM) + kt * 64);
        }
        __syncthreads();

        bf16x8 af[2][4], bfr[2][4];
#pragma unroll
        for (int kh = 0; kh < 2; ++kh)
#pragma unroll
            for (int i = 0; i < 4; ++i) {
                af[kh][i]  = *(const bf16x8*)swz(As, wm + i * 16 + l15, kh * 4 + quad);
                bfr[kh][i] = *(const bf16x8*)swz(Bs, wn + i * 16 + l15, kh * 4 + quad);
            }
#pragma unroll
        for (int kh = 0; kh < 2; ++kh)
#pragma unroll
            for (int i = 0; i < 4; ++i)
#pragma unroll
                for (int j = 0; j < 4; ++j)
                    acc[i][j] = __builtin_amdgcn_mfma_f32_16x16x32_bf16(af[kh][i], bfr[kh][j], acc[i][j], 0, 0, 0);
    }

    const int b = bm0 >> 11, nbase = bm0 & 2047;

    if (bn0 < 512) {            // pure-Q block
#pragma unroll
        for (int i = 0; i < 4; ++i)
#pragma unroll
            for (int j = 0; j < 4; ++j)
#pragma unroll
                for (int r = 0; r < 4; ++r) {
                    const int row = bm0 + wm + i * 16 + quad * 4 + r;
                    const int col = bn0 + wn + j * 16 + l15;
                    const int h = col >> 6, d = col & 63;
                    const int n = row & 2047;
                    const size_t idx = (((size_t)((row >> 11) * NH + h)) * SEQ + n) * HD + d;
                    Q[idx] = (bf16)(acc[i][j][r] * QSCALE);
                }
    } else if (bn0 < 1024) {    // pure-K block (half-swap rows n&8)
#pragma unroll
        for (int i = 0; i < 4; ++i)
#pragma unroll
            for (int j = 0; j < 4; ++j)
#pragma unroll
                for (int r = 0; r < 4; ++r) {
                    const int row = bm0 + wm + i * 16 + quad * 4 + r;
                    const int col = bn0 - 512 + wn + j * 16 + l15;
                    const int h = col >> 6, d = col & 63;
                    const int n = row & 2047;
                    const size_t idx = (((size_t)((row >> 11) * NH + h)) * SEQ + n) * HD + d;
                    Kv[idx ^ (size_t)((n >> 1) & 4)] = (bf16)acc[i][j][r];
                }
    } else {
        __syncthreads();
        bf16 (*Ts)[136] = (bf16(*)[136])smraw;
#pragma unroll
        for (int i = 0; i < 4; ++i)
#pragma unroll
            for (int j = 0; j < 4; ++j) {
                bf16x4 pk = {(bf16)acc[i][j][0], (bf16)acc[i][j][1],
                             (bf16)acc[i][j][2], (bf16)acc[i][j][3]};
                *(bf16x4*)&Ts[wn + j * 16 + l15][wm + i * 16 + quad * 4] = pk;
            }
        __syncthreads();
        const int cb = bn0 - 1024;
#pragma unroll
        for (int t2 = 0; t2 < 8; ++t2) {
            const int id2 = tid + t2 * 256;
            const int c = id2 >> 4, nc = (id2 & 15) * 8;
            const int col = cb + c;
            const int h = col >> 6, d = col & 63;
            bf16x8 val = *(const bf16x8*)&Ts[c][nc];
            if (d & 8)  // half-swap rows d&8 (4-key halves within 8-key chunk)
                val = __builtin_shufflevector(val, val, 4, 5, 6, 7, 0, 1, 2, 3);
            *(bf16x8*)&VT[(((size_t)(b * NH + h)) * HD + d) * SEQ + nbase + nc] = val;
        }
    }
}

// ---------------------------------------------------------------------------
// Kernel 2: flash attention (R8 = R1's verified 50.4us structure).
// 512 blocks (32 bh x 16 qt), 4 waves x 32 q-rows, KVBLK=64 dbuf, single
// s/o accumulators (R7's ILP splits REVERTED — they lengthened the VALU
// critical path). Only deltas vs R1: ld_swz8 reads (verified R6/R7,
// conflicts halved) and T5 setprio around MFMA clusters (m191: attn +4-7%).
// ---------------------------------------------------------------------------
__global__ __launch_bounds__(256, 4) void attn(const bf16* __restrict__ Q,
                                               const bf16* __restrict__ K,
                                               const bf16* __restrict__ VT,
                                               bf16* __restrict__ Y) {
    __shared__ bf16 Ks[2][64 * 64];    // 16 KB: 64 keys x 64 d
    __shared__ bf16 VTs[2][64 * 64];   // 16 KB: 64 d x 64 keys

    const int tid  = threadIdx.x;
    const int wave = tid >> 6, lane = tid & 63;   // 4 waves x 32 q-rows
    const int l31  = lane & 31, hi = lane >> 5;
    const int bh = blockIdx.x;                 // bh fast dim: same-XCD L2 reuse
    const int q0 = blockIdx.y * 128;
    const bf16* Qg = Q  + (size_t)bh * SEQ * HD;
    const bf16* Kg = K  + (size_t)bh * SEQ * HD;
    const bf16* Vg = VT + (size_t)bh * HD * SEQ;

    // Q fragments for this wave's 32 q-rows
    bf16x8 aq[4];
    {
        const bf16* qrow = Qg + (size_t)(q0 + wave * 32 + l31) * HD;
#pragma unroll
        for (int c = 0; c < 4; ++c)
            aq[c] = *(const bf16x8*)(qrow + c * 16 + hi * 8);
    }

    // staging lanes: 8 rows x 8 chunks per cp16; 4 waves x 16 rows = 64 rows
    const int r8 = lane >> 3, cc8 = (lane & 7) ^ r8;
    const bf16* kgw = Kg + (size_t)(wave * 16 + r8) * HD + cc8 * 8;
    const bf16* vgw = Vg + (size_t)(wave * 16 + r8) * SEQ + cc8 * 8;

    float l = 0.f;
    floatx16 o[2];
#pragma unroll
    for (int i = 0; i < 16; ++i) { o[0][i] = 0.f; o[1][i] = 0.f; }

    // prologue: stage tile 0 (64 keys: K 8KB + V 8KB, 4 cp16/thread)
#pragma unroll
    for (int it = 0; it < 2; ++it) {
        cp16(&Ks[0][(wave * 16 + it * 8) * 64], kgw + (size_t)(it * 8) * HD);
        cp16(&VTs[0][(wave * 16 + it * 8) * 64], vgw + (size_t)(it * 8) * SEQ);
    }

    for (int kt = 0; kt < SEQ / 64; ++kt) {
        const int cur = kt & 1;
        __syncthreads();   // drains DMA(kt) (issued one iter ago)
        if (kt < SEQ / 64 - 1) {
#pragma unroll
            for (int it = 0; it < 2; ++it) {
                cp16(&Ks[cur ^ 1][(wave * 16 + it * 8) * 64],
                     kgw + (size_t)((kt + 1) * 64 + it * 8) * HD);
                cp16(&VTs[cur ^ 1][(wave * 16 + it * 8) * 64],
                     vgw + (size_t)(it * 8) * SEQ + (kt + 1) * 64);
            }
        }

#pragma unroll
        for (int kb = 0; kb < 2; ++kb) {
            const int krow = kb * 32 + l31;
            bf16x8 kf[4];
#pragma unroll
            for (int c = 0; c < 4; ++c)
                kf[c] = ld_swz8(Ks[cur], krow, c * 2 + hi);
            bf16x8 vf[2][2];
#pragma unroll
            for (int db = 0; db < 2; ++db) {
                vf[db][0] = ld_swz8(VTs[cur], db * 32 + l31, kb * 4 + hi);
                vf[db][1] = ld_swz8(VTs[cur], db * 32 + l31, kb * 4 + 2 + hi);
            }

            // S^T = K * Q : lane owns q-row l31, keys kb*32 + ...
            floatx16 s;
#pragma unroll
            for (int i = 0; i < 16; ++i) s[i] = 0.f;
            __builtin_amdgcn_s_setprio(1);
#pragma unroll
            for (int c = 0; c < 4; ++c)
                s = __builtin_amdgcn_mfma_f32_32x32x16_bf16(kf[c], aq[c], s, 0, 0, 0);
            __builtin_amdgcn_s_setprio(0);
            // softmax numerator in-register
            float p[16];
#pragma unroll
            for (int i = 0; i < 16; ++i) p[i] = __builtin_amdgcn_exp2f(s[i]);
            {
                const float t0 = (p[0] + p[1]) + (p[2] + p[3]);
                const float t1 = (p[4] + p[5]) + (p[6] + p[7]);
                const float t2 = (p[8] + p[9]) + (p[10] + p[11]);
                const float t3 = (p[12] + p[13]) + (p[14] + p[15]);
                l += (t0 + t1) + (t2 + t3);
            }
            int w[8];
#pragma unroll
            for (int i = 0; i < 8; ++i) w[i] = cvtpk_bf16(p[2 * i], p[2 * i + 1]);
            plswap(w[0], w[2]); plswap(w[1], w[3]);
            plswap(w[4], w[6]); plswap(w[5], w[7]);
            const int4v f0i = {w[0], w[1], w[2], w[3]};
            const int4v f1i = {w[4], w[5], w[6], w[7]};
            const bf16x8 f0 = __builtin_bit_cast(bf16x8, f0i);
            const bf16x8 f1 = __builtin_bit_cast(bf16x8, f1i);
            __builtin_amdgcn_s_setprio(1);
#pragma unroll
            for (int db = 0; db < 2; ++db) {
                o[db] = __builtin_amdgcn_mfma_f32_32x32x16_bf16(f0, vf[db][0], o[db], 0, 0, 0);
                o[db] = __builtin_amdgcn_mfma_f32_32x32x16_bf16(f1, vf[db][1], o[db], 0, 0, 0);
            }
            __builtin_amdgcn_s_setprio(0);
        }
    }

    // epilogue (R1-verified): finish row sums, distribute 1/l, write Y
    l += __shfl_xor(l, 32, 64);           // merge hi-halves: full 2048-key sum
    const float inv = 1.0f / l;
    const int b = bh >> 3, h = bh & 7;
#pragma unroll
    for (int reg = 0; reg < 16; ++reg) {
        const int qr = (reg & 3) + 8 * (reg >> 2) + 4 * hi;
        const float li = __int_as_float(
            __builtin_amdgcn_ds_bpermute(qr << 2, __float_as_int(inv)));
        const int n = q0 + wave * 32 + qr;
        bf16* yrow = Y + ((size_t)(b * SEQ + n)) * ATT_DIM + h * HD + l31;
        yrow[0]  = (bf16)(o[0][reg] * li);
        yrow[32] = (bf16)(o[1][reg] * li);
    }
}

// ---------------------------------------------------------------------------
// Kernel 3: out = Y * Woutb^T + b_out (bf16 DMA-staged, BK=64, fp32 out).
// R8: T1 XCD-chunked swizzle (nwg=384, 384%8==0 -> bijective): per XCD,
// B (W_out, 0.77 MB) L2-resident, 8 contiguous M-panels x 6 N-blocks.
// ---------------------------------------------------------------------------
__global__ __launch_bounds__(256) void out_gemm(const bf16* __restrict__ Yb,
                                                const bf16* __restrict__ Wb,
                                                const float* __restrict__ bias,
                                                float* __restrict__ out) {
    __shared__ __align__(16) bf16 As[128 * 64];
    __shared__ __align__(16) bf16 Bs[128 * 64];

    const int tid  = threadIdx.x;
    const int id  = blockIdx.y * 6 + blockIdx.x;    // gridDim.x == 6
    const int nid = (id & 7) * 48 + (id >> 3);
    const int bm0 = (nid / 6) * 128;
    const int bn0 = (nid % 6) * 128;
    const int wave = tid >> 6, lane = tid & 63;
    const int quad = lane >> 4, l15 = lane & 15;
    const int wm = (wave >> 1) * 64, wn = (wave & 1) * 64;
    const int r8 = lane >> 3, cc = (lane & 7) ^ r8;

    const bf16* ag = Yb + (size_t)(bm0 + wave * 32 + r8) * ATT_DIM + cc * 8;
    const bf16* bg = Wb + (size_t)(bn0 + wave * 32 + r8) * ATT_DIM + cc * 8;

    floatx4 acc[4][4];
#pragma unroll
    for (int i = 0; i < 4; ++i)
#pragma unroll
        for (int j = 0; j < 4; ++j) acc[i][j] = (floatx4){0.f, 0.f, 0.f, 0.f};

    for (int kt = 0; kt < ATT_DIM / 64; ++kt) {
        __syncthreads();
#pragma unroll
        for (int it = 0; it < 4; ++it) {
            cp16(&As[(wave * 32 + it * 8) * 64], ag + it * (8 * ATT_DIM) + kt * 64);
            cp16(&Bs[(wave * 32 + it * 8) * 64], bg + it * (8 * ATT_DIM) + kt * 64);
        }
        __syncthreads();

        bf16x8 af[2][4], bfr[2][4];
#pragma unroll
        for (int kh = 0; kh < 2; ++kh)
#pragma unroll
            for (int i = 0; i < 4; ++i) {
                af[kh][i]  = *(const bf16x8*)swz(As, wm + i * 16 + l15, kh * 4 + quad);
                bfr[kh][i] = *(const bf16x8*)swz(Bs, wn + i * 16 + l15, kh * 4 + quad);
            }
#pragma unroll
        for (int kh = 0; kh < 2; ++kh)
#pragma unroll
            for (int i = 0; i < 4; ++i)
#pragma unroll
                for (int j = 0; j < 4; ++j)
                    acc[i][j] = __builtin_amdgcn_mfma_f32_16x16x32_bf16(af[kh][i], bfr[kh][j], acc[i][j], 0, 0, 0);
    }

#pragma unroll
    for (int i = 0; i < 4; ++i)
#pragma unroll
        for (int j = 0; j < 4; ++j)
#pragma unroll
            for (int r = 0; r < 4; ++r) {
                const int row = bm0 + wm + i * 16 + quad * 4 + r;
                const int col = bn0 + wn + j * 16 + l15;
                out[(size_t)row * IN_DIM + col] = acc[i][j][r] + bias[col];
            }
}

// ---------------------------------------------------------------------------
extern "C" void kernel_launch(void* const* d_in, const int* in_sizes, int n_in,
                              void* d_out, int out_size, void* d_ws, size_t ws_size,
                              hipStream_t stream) {
    const float* X    = (const float*)d_in[0];
    const float* Wqkv = (const float*)d_in[1];
    const float* Wout = (const float*)d_in[2];
    const float* bout = (const float*)d_in[3];
    float* out = (float*)d_out;

    char* ws = (char*)d_ws;
    size_t off = 0;
    bf16* Xb  = (bf16*)(ws + off); off += (size_t)M_TOT * IN_DIM * 2;
    bf16* Wqb = (bf16*)(ws + off); off += (size_t)QKV_N * IN_DIM * 2;
    bf16* Wob = (bf16*)(ws + off); off += (size_t)IN_DIM * ATT_DIM * 2;
    const size_t T = (size_t)BATCH * NH * SEQ * HD * 2;
    bf16* Q  = (bf16*)(ws + off); off += T;
    bf16* K  = (bf16*)(ws + off); off += T;
    bf16* VT = (bf16*)(ws + off); off += T;
    bf16* Y  = (bf16*)(ws + off); off += T;

    cvt_all<<<N8_ALL / 256, 256, 0, stream>>>(X, Wqkv, Wout, Xb, Wqb, Wob);
    qkv_gemm<<<dim3(QKV_N / 128, M_TOT / 128), 256, 0, stream>>>(Xb, Wqb, Q, K, VT);
    attn<<<dim3(BATCH * NH, SEQ / 128), 256, 0, stream>>>(Q, K, VT, Y);
    out_gemm<<<dim3(IN_DIM / 128, M_TOT / 128), 256, 0, stream>>>(Y, Wob, bout, out);
}

// Round 9
// 157.937 us; speedup vs baseline: 1.2614x; 1.0573x over previous
//
#include <hip/hip_runtime.h>

typedef __bf16 bf16;
typedef unsigned int u32;
typedef __attribute__((ext_vector_type(8))) __bf16 bf16x8;
typedef __attribute__((ext_vector_type(4))) __bf16 bf16x4;
typedef __attribute__((ext_vector_type(4))) float floatx4;
typedef __attribute__((ext_vector_type(16))) float floatx16;
typedef __attribute__((ext_vector_type(4))) int int4v;

#define IN_DIM  768
#define ATT_DIM 512
#define NH      8
#define HD      64
#define BATCH   4
#define SEQ     2048
#define M_TOT   (BATCH*SEQ)     // 8192
#define QKV_N   (3*ATT_DIM)     // 1536

// Q scale: 1/sqrt(64) * log2(e)  -> scores exit MFMA in log2 domain
#define QSCALE 0.18033688011112042f

// async 16B global->LDS copy. LDS dest = wave-uniform base + lane*16.
__device__ __forceinline__ void cp16(void* lds, const void* g) {
    __builtin_amdgcn_global_load_lds((const __attribute__((address_space(1))) u32*)g,
                                     (__attribute__((address_space(3))) u32*)lds, 16, 0, 0);
}
// XOR-swizzled accessor for 64-col bf16 tiles staged by cp16:
// 16B chunk c (0..7) of row r lives at slot c ^ (r&7).
__device__ __forceinline__ const bf16* swz(const bf16* b, int row, int chunk) {
    return b + row * 64 + (((chunk) ^ (row & 7)) << 3);
}

// pack two f32 -> one dword of 2 bf16 (low = lo, high = hi)
__device__ __forceinline__ int cvtpk_bf16(float lo, float hi) {
    int r;
    asm("v_cvt_pk_bf16_f32 %0, %1, %2" : "=v"(r) : "v"(lo), "v"(hi));
    return r;
}
// v_permlane32_swap_b32: a.hi-half <-> b.lo-half.
__device__ __forceinline__ void plswap(int& a, int& b) {
    asm("v_permlane32_swap_b32 %0, %1" : "+v"(a), "+v"(b));
}

// ---------------------------------------------------------------------------
// Kernel 0: fp32 -> bf16 conversion of X, W_qkv, W_out
// ---------------------------------------------------------------------------
#define N8_X  (M_TOT * IN_DIM / 8)
#define N8_WQ (QKV_N * IN_DIM / 8)
#define N8_WO (IN_DIM * ATT_DIM / 8)
#define N8_ALL (N8_X + N8_WQ + N8_WO)

__global__ __launch_bounds__(256) void cvt_all(const float* __restrict__ X,
                                               const float* __restrict__ Wq,
                                               const float* __restrict__ Wo,
                                               bf16* __restrict__ Xb,
                                               bf16* __restrict__ Wqb,
                                               bf16* __restrict__ Wob) {
    int i = blockIdx.x * 256 + threadIdx.x;
    const float* s; bf16* d; int off;
    if (i < N8_X)            { s = X;  d = Xb;  off = i; }
    else if (i < N8_X+N8_WQ) { s = Wq; d = Wqb; off = i - N8_X; }
    else                     { s = Wo; d = Wob; off = i - N8_X - N8_WQ; }
    const float4 a = ((const float4*)s)[2*off];
    const float4 b = ((const float4*)s)[2*off+1];
    bf16x8 o = {(bf16)a.x,(bf16)a.y,(bf16)a.z,(bf16)a.w,
                (bf16)b.x,(bf16)b.y,(bf16)b.z,(bf16)b.w};
    ((bf16x8*)d)[off] = o;
}

// ---------------------------------------------------------------------------
// Kernel 1: QKV = Xb * Wqkvb^T (bf16, DMA-staged, BK=64).
// R9: layouts reverted to R1-plain (no half-swaps — attn uses b128 swz reads
// again). Keeps R8's T1 XCD-chunked swizzle (nwg=768, bijective: each XCD
// gets 8 contiguous M-panels x all 12 N-blocks; B L2-resident per XCD) and
// the block-uniform epilogue branches.
// Q -> [b][h][n][d] (pre-scaled); K -> [b][h][n][d]; V -> [b][h][d][n].
// ---------------------------------------------------------------------------
__global__ __launch_bounds__(256) void qkv_gemm(const bf16* __restrict__ Xb,
                                                const bf16* __restrict__ Wb,
                                                bf16* __restrict__ Q,
                                                bf16* __restrict__ Kv,
                                                bf16* __restrict__ VT) {
    __shared__ __align__(16) char smraw[34816];
    bf16* As = (bf16*)smraw;
    bf16* Bs = (bf16*)(smraw + 16384);

    const int tid  = threadIdx.x;
    // XCD-chunked swizzle: dispatch id -> tile id (96 tiles per XCD chunk)
    const int id  = blockIdx.y * 12 + blockIdx.x;   // gridDim.x == 12
    const int nid = (id & 7) * 96 + (id >> 3);
    const int bm0 = (nid / 12) * 128;
    const int bn0 = (nid % 12) * 128;
    const int wave = tid >> 6, lane = tid & 63;
    const int quad = lane >> 4, l15 = lane & 15;
    const int wm = (wave >> 1) * 64, wn = (wave & 1) * 64;
    const int r8 = lane >> 3, cc = (lane & 7) ^ r8;

    const bf16* ag = Xb + (size_t)(bm0 + wave * 32 + r8) * IN_DIM + cc * 8;
    const bf16* bg = Wb + (size_t)(bn0 + wave * 32 + r8) * IN_DIM + cc * 8;

    floatx4 acc[4][4];
#pragma unroll
    for (int i = 0; i < 4; ++i)
#pragma unroll
        for (int j = 0; j < 4; ++j) acc[i][j] = (floatx4){0.f, 0.f, 0.f, 0.f};

    for (int kt = 0; kt < IN_DIM / 64; ++kt) {
        __syncthreads();
#pragma unroll
        for (int it = 0; it < 4; ++it) {
            cp16(&As[(wave * 32 + it * 8) * 64], ag + it * (8 * IN_DIM) + kt * 64);
            cp16(&Bs[(wave * 32 + it * 8) * 64], bg + it * (8 * IN_DIM) + kt * 64);
        }
        __syncthreads();

        bf16x8 af[2][4], bfr[2][4];
#pragma unroll
        for (int kh = 0; kh < 2; ++kh)
#pragma unroll
            for (int i = 0; i < 4; ++i) {
                af[kh][i]  = *(const bf16x8*)swz(As, wm + i * 16 + l15, kh * 4 + quad);
                bfr[kh][i] = *(const bf16x8*)swz(Bs, wn + i * 16 + l15, kh * 4 + quad);
            }
#pragma unroll
        for (int kh = 0; kh < 2; ++kh)
#pragma unroll
            for (int i = 0; i < 4; ++i)
#pragma unroll
                for (int j = 0; j < 4; ++j)
                    acc[i][j] = __builtin_amdgcn_mfma_f32_16x16x32_bf16(af[kh][i], bfr[kh][j], acc[i][j], 0, 0, 0);
    }

    const int b = bm0 >> 11, nbase = bm0 & 2047;

    if (bn0 < 512) {            // pure-Q block
#pragma unroll
        for (int i = 0; i < 4; ++i)
#pragma unroll
            for (int j = 0; j < 4; ++j)
#pragma unroll
                for (int r = 0; r < 4; ++r) {
                    const int row = bm0 + wm + i * 16 + quad * 4 + r;
                    const int col = bn0 + wn + j * 16 + l15;
                    const int h = col >> 6, d = col & 63;
                    const int n = row & 2047;
                    const size_t idx = (((size_t)((row >> 11) * NH + h)) * SEQ + n) * HD + d;
                    Q[idx] = (bf16)(acc[i][j][r] * QSCALE);
                }
    } else if (bn0 < 1024) {    // pure-K block (plain layout)
#pragma unroll
        for (int i = 0; i < 4; ++i)
#pragma unroll
            for (int j = 0; j < 4; ++j)
#pragma unroll
                for (int r = 0; r < 4; ++r) {
                    const int row = bm0 + wm + i * 16 + quad * 4 + r;
                    const int col = bn0 - 512 + wn + j * 16 + l15;
                    const int h = col >> 6, d = col & 63;
                    const int n = row & 2047;
                    const size_t idx = (((size_t)((row >> 11) * NH + h)) * SEQ + n) * HD + d;
                    Kv[idx] = (bf16)acc[i][j][r];
                }
    } else {
        __syncthreads();
        bf16 (*Ts)[136] = (bf16(*)[136])smraw;
#pragma unroll
        for (int i = 0; i < 4; ++i)
#pragma unroll
            for (int j = 0; j < 4; ++j) {
                bf16x4 pk = {(bf16)acc[i][j][0], (bf16)acc[i][j][1],
                             (bf16)acc[i][j][2], (bf16)acc[i][j][3]};
                *(bf16x4*)&Ts[wn + j * 16 + l15][wm + i * 16 + quad * 4] = pk;
            }
        __syncthreads();
        const int cb = bn0 - 1024;
#pragma unroll
        for (int t2 = 0; t2 < 8; ++t2) {
            const int id2 = tid + t2 * 256;
            const int c = id2 >> 4, nc = (id2 & 15) * 8;
            const int col = cb + c;
            const int h = col >> 6, d = col & 63;
            *(bf16x8*)&VT[(((size_t)(b * NH + h)) * HD + d) * SEQ + nbase + nc] =
                *(const bf16x8*)&Ts[c][nc];
        }
    }
}

// ---------------------------------------------------------------------------
// Kernel 2: flash attention — EXACT R1 structure (verified 50.4 us).
// 512 blocks (32 bh x 16 qt), 4 waves x 32 q-rows, KVBLK=64 dbuf, b128 swz
// fragment reads, single s/o accumulators, no setprio (R8 attribution:
// ld_swz8/setprio cost +6.2 us vs this), direct-Y epilogue.
// ---------------------------------------------------------------------------
__global__ __launch_bounds__(256, 4) void attn(const bf16* __restrict__ Q,
                                               const bf16* __restrict__ K,
                                               const bf16* __restrict__ VT,
                                               bf16* __restrict__ Y) {
    __shared__ bf16 Ks[2][64 * 64];    // 16 KB: 64 keys x 64 d, swz
    __shared__ bf16 VTs[2][64 * 64];   // 16 KB: 64 d x 64 keys, swz

    const int tid  = threadIdx.x;
    const int wave = tid >> 6, lane = tid & 63;
    const int l31  = lane & 31, hi = lane >> 5;
    const int bh = blockIdx.x;                 // bh fast dim: same-XCD L2 reuse
    const int q0 = blockIdx.y * 128;
    const bf16* Qg = Q  + (size_t)bh * SEQ * HD;
    const bf16* Kg = K  + (size_t)bh * SEQ * HD;
    const bf16* Vg = VT + (size_t)bh * HD * SEQ;

    // Q fragments (B-operand, col=q=lane&31, k(d)=hi*8+j): 4 chains over D=64
    bf16x8 aq[4];
    {
        const bf16* qrow = Qg + (size_t)(q0 + wave * 32 + l31) * HD;
#pragma unroll
        for (int c = 0; c < 4; ++c)
            aq[c] = *(const bf16x8*)(qrow + c * 16 + hi * 8);
    }

    // staging lanes: 8 rows x 8 chunks, chunk swizzle (row&7)
    const int r8 = lane >> 3, cc8 = (lane & 7) ^ r8;
    const bf16* kgw = Kg + (size_t)(wave * 16 + r8) * HD + cc8 * 8;
    const bf16* vgw = Vg + (size_t)(wave * 16 + r8) * SEQ + cc8 * 8;

    float l = 0.f;
    floatx16 o[2];
#pragma unroll
    for (int i = 0; i < 16; ++i) { o[0][i] = 0.f; o[1][i] = 0.f; }

    // prologue: stage tile 0 (64 keys: K 8KB + V 8KB, 4 cp16/thread)
#pragma unroll
    for (int it = 0; it < 2; ++it) {
        cp16(&Ks[0][(wave * 16 + it * 8) * 64], kgw + (size_t)(it * 8) * HD);
        cp16(&VTs[0][(wave * 16 + it * 8) * 64], vgw + (size_t)(it * 8) * SEQ);
    }

    for (int kt = 0; kt < SEQ / 64; ++kt) {
        const int cur = kt & 1;
        __syncthreads();   // drains DMA(kt) (issued one iter ago)
        if (kt < SEQ / 64 - 1) {
#pragma unroll
            for (int it = 0; it < 2; ++it) {
                cp16(&Ks[cur ^ 1][(wave * 16 + it * 8) * 64],
                     kgw + (size_t)((kt + 1) * 64 + it * 8) * HD);
                cp16(&VTs[cur ^ 1][(wave * 16 + it * 8) * 64],
                     vgw + (size_t)(it * 8) * SEQ + (kt + 1) * 64);
            }
        }

#pragma unroll
        for (int kb = 0; kb < 2; ++kb) {
            // S^T = K * Q  (D[row=key][col=q]); K A-operand: row=key=kb*32+l31
            const int krow = kb * 32 + l31;
            floatx16 s;
#pragma unroll
            for (int i = 0; i < 16; ++i) s[i] = 0.f;
#pragma unroll
            for (int c = 0; c < 4; ++c) {
                const bf16x8 kf = *(const bf16x8*)swz(Ks[cur], krow, c * 2 + hi);
                s = __builtin_amdgcn_mfma_f32_32x32x16_bf16(kf, aq[c], s, 0, 0, 0);
            }
            // softmax numerator, fully in-register. lane q = l31,
            // keys(reg) = kb*32 + (reg&3) + 8*(reg>>2) + 4*hi
            float p[16];
#pragma unroll
            for (int i = 0; i < 16; ++i) p[i] = __builtin_amdgcn_exp2f(s[i]);
            {
                const float t0 = (p[0] + p[1]) + (p[2] + p[3]);
                const float t1 = (p[4] + p[5]) + (p[6] + p[7]);
                const float t2 = (p[8] + p[9]) + (p[10] + p[11]);
                const float t3 = (p[12] + p[13]) + (p[14] + p[15]);
                l += (t0 + t1) + (t2 + t3);
            }
            // pack pairs: w[i] = bf16x2 of keys {base+2i, base+2i+1} per hi-half
            int w[8];
#pragma unroll
            for (int i = 0; i < 8; ++i) w[i] = cvtpk_bf16(p[2 * i], p[2 * i + 1]);
            // half-swaps: after these, [w0..w3] = A-frag keys kb*32+0..15,
            // [w4..w7] = A-frag keys kb*32+16..31 (k = hi*8 + j)
            plswap(w[0], w[2]); plswap(w[1], w[3]);
            plswap(w[4], w[6]); plswap(w[5], w[7]);
            const int4v f0i = {w[0], w[1], w[2], w[3]};
            const int4v f1i = {w[4], w[5], w[6], w[7]};
            const bf16x8 f0 = __builtin_bit_cast(bf16x8, f0i);
            const bf16x8 f1 = __builtin_bit_cast(bf16x8, f1i);
            // O += P * V ; V B-operand from VTs: col=d=db*32+l31, keys chunked
#pragma unroll
            for (int db = 0; db < 2; ++db) {
                const int vrow = db * 32 + l31;
                const bf16x8 v0 = *(const bf16x8*)swz(VTs[cur], vrow, kb * 4 + hi);
                const bf16x8 v1 = *(const bf16x8*)swz(VTs[cur], vrow, kb * 4 + 2 + hi);
                o[db] = __builtin_amdgcn_mfma_f32_32x32x16_bf16(f0, v0, o[db], 0, 0, 0);
                o[db] = __builtin_amdgcn_mfma_f32_32x32x16_bf16(f1, v1, o[db], 0, 0, 0);
            }
        }
    }

    // epilogue: finish row sums, distribute 1/l, write Y
    l += __shfl_xor(l, 32, 64);
    const float inv = 1.0f / l;
    const int b = bh >> 3, h = bh & 7;
#pragma unroll
    for (int reg = 0; reg < 16; ++reg) {
        const int qr = (reg & 3) + 8 * (reg >> 2) + 4 * hi;
        const float li = __int_as_float(
            __builtin_amdgcn_ds_bpermute(qr << 2, __float_as_int(inv)));
        const int n = q0 + wave * 32 + qr;
        bf16* yrow = Y + ((size_t)(b * SEQ + n)) * ATT_DIM + h * HD + l31;
        yrow[0]  = (bf16)(o[0][reg] * li);
        yrow[32] = (bf16)(o[1][reg] * li);
    }
}

// ---------------------------------------------------------------------------
// Kernel 3: out = Y * Woutb^T + b_out (bf16 DMA-staged, BK=64, fp32 out).
// R8-verified: T1 XCD-chunked swizzle (nwg=384, bijective): per XCD,
// B (W_out, 0.77 MB) L2-resident, 8 contiguous M-panels x 6 N-blocks.
// ---------------------------------------------------------------------------
__global__ __launch_bounds__(256) void out_gemm(const bf16* __restrict__ Yb,
                                                const bf16* __restrict__ Wb,
                                                const float* __restrict__ bias,
                                                float* __restrict__ out) {
    __shared__ __align__(16) bf16 As[128 * 64];
    __shared__ __align__(16) bf16 Bs[128 * 64];

    const int tid  = threadIdx.x;
    const int id  = blockIdx.y * 6 + blockIdx.x;    // gridDim.x == 6
    const int nid = (id & 7) * 48 + (id >> 3);
    const int bm0 = (nid / 6) * 128;
    const int bn0 = (nid % 6) * 128;
    const int wave = tid >> 6, lane = tid & 63;
    const int quad = lane >> 4, l15 = lane & 15;
    const int wm = (wave >> 1) * 64, wn = (wave & 1) * 64;
    const int r8 = lane >> 3, cc = (lane & 7) ^ r8;

    const bf16* ag = Yb + (size_t)(bm0 + wave * 32 + r8) * ATT_DIM + cc * 8;
    const bf16* bg = Wb + (size_t)(bn0 + wave * 32 + r8) * ATT_DIM + cc * 8;

    floatx4 acc[4][4];
#pragma unroll
    for (int i = 0; i < 4; ++i)
#pragma unroll
        for (int j = 0; j < 4; ++j) acc[i][j] = (floatx4){0.f, 0.f, 0.f, 0.f};

    for (int kt = 0; kt < ATT_DIM / 64; ++kt) {
        __syncthreads();
#pragma unroll
        for (int it = 0; it < 4; ++it) {
            cp16(&As[(wave * 32 + it * 8) * 64], ag + it * (8 * ATT_DIM) + kt * 64);
            cp16(&Bs[(wave * 32 + it * 8) * 64], bg + it * (8 * ATT_DIM) + kt * 64);
        }
        __syncthreads();

        bf16x8 af[2][4], bfr[2][4];
#pragma unroll
        for (int kh = 0; kh < 2; ++kh)
#pragma unroll
            for (int i = 0; i < 4; ++i) {
                af[kh][i]  = *(const bf16x8*)swz(As, wm + i * 16 + l15, kh * 4 + quad);
                bfr[kh][i] = *(const bf16x8*)swz(Bs, wn + i * 16 + l15, kh * 4 + quad);
            }
#pragma unroll
        for (int kh = 0; kh < 2; ++kh)
#pragma unroll
            for (int i = 0; i < 4; ++i)
#pragma unroll
                for (int j = 0; j < 4; ++j)
                    acc[i][j] = __builtin_amdgcn_mfma_f32_16x16x32_bf16(af[kh][i], bfr[kh][j], acc[i][j], 0, 0, 0);
    }

#pragma unroll
    for (int i = 0; i < 4; ++i)
#pragma unroll
        for (int j = 0; j < 4; ++j)
#pragma unroll
            for (int r = 0; r < 4; ++r) {
                const int row = bm0 + wm + i * 16 + quad * 4 + r;
                const int col = bn0 + wn + j * 16 + l15;
                out[(size_t)row * IN_DIM + col] = acc[i][j][r] + bias[col];
            }
}

// ---------------------------------------------------------------------------
extern "C" void kernel_launch(void* const* d_in, const int* in_sizes, int n_in,
                              void* d_out, int out_size, void* d_ws, size_t ws_size,
                              hipStream_t stream) {
    const float* X    = (const float*)d_in[0];
    const float* Wqkv = (const float*)d_in[1];
    const float* Wout = (const float*)d_in[2];
    const float* bout = (const float*)d_in[3];
    float* out = (float*)d_out;

    char* ws = (char*)d_ws;
    size_t off = 0;
    bf16* Xb  = (bf16*)(ws + off); off += (size_t)M_TOT * IN_DIM * 2;
    bf16* Wqb = (bf16*)(ws + off); off += (size_t)QKV_N * IN_DIM * 2;
    bf16* Wob = (bf16*)(ws + off); off += (size_t)IN_DIM * ATT_DIM * 2;
    const size_t T = (size_t)BATCH * NH * SEQ * HD * 2;
    bf16* Q  = (bf16*)(ws + off); off += T;
    bf16* K  = (bf16*)(ws + off); off += T;
    bf16* VT = (bf16*)(ws + off); off += T;
    bf16* Y  = (bf16*)(ws + off); off += T;

    cvt_all<<<N8_ALL / 256, 256, 0, stream>>>(X, Wqkv, Wout, Xb, Wqb, Wob);
    qkv_gemm<<<dim3(QKV_N / 128, M_TOT / 128), 256, 0, stream>>>(Xb, Wqb, Q, K, VT);
    attn<<<dim3(BATCH * NH, SEQ / 128), 256, 0, stream>>>(Q, K, VT, Y);
    out_gemm<<<dim3(IN_DIM / 128, M_TOT / 128), 256, 0, stream>>>(Y, Wob, bout, out);
}